// Round 1
// baseline (581.625 us; speedup 1.0000x reference)
//
#include <hip/hip_runtime.h>
#include <hip/hip_bf16.h>

typedef __attribute__((ext_vector_type(8))) short short8;
typedef __attribute__((ext_vector_type(4))) float f32x4;

#define GL2LDS16(g, l)                                                         \
  __builtin_amdgcn_global_load_lds(                                            \
      (const __attribute__((address_space(1))) unsigned int*)(g),              \
      (__attribute__((address_space(3))) unsigned int*)(l), 16, 0, 0)

// ---------------------------------------------------------------------------
// feat[row][0:1024] = x_m[m_ids[row]]; feat[row][1024:2048] = x_op[op_idx[row]]
// (bf16). Also srow[row] = job_srpt[job_ids[row]] (fp32).
// ---------------------------------------------------------------------------
__global__ __launch_bounds__(256) void feat_kernel(
    const float* __restrict__ x_m, const float* __restrict__ x_op,
    const float* __restrict__ job_srpt, const int* __restrict__ m_ids,
    const int* __restrict__ op_idx, const int* __restrict__ job_ids,
    __hip_bfloat16* __restrict__ feat, float* __restrict__ srow) {
  const int row = blockIdx.x;
  const int t = threadIdx.x;
  const int j0 = t * 8;
  const float* src;
  if (j0 < 1024)
    src = x_m + (long)m_ids[row] * 1024 + j0;
  else
    src = x_op + (long)op_idx[row] * 1024 + (j0 - 1024);
  float4 v0 = *(const float4*)src;
  float4 v1 = *(const float4*)(src + 4);
  union {
    __hip_bfloat16 h[8];
    int4 i4;
  } u;
  u.h[0] = __float2bfloat16(v0.x);
  u.h[1] = __float2bfloat16(v0.y);
  u.h[2] = __float2bfloat16(v0.z);
  u.h[3] = __float2bfloat16(v0.w);
  u.h[4] = __float2bfloat16(v1.x);
  u.h[5] = __float2bfloat16(v1.y);
  u.h[6] = __float2bfloat16(v1.z);
  u.h[7] = __float2bfloat16(v1.w);
  *(int4*)&feat[(long)row * 2048 + j0] = u.i4;
  if (t == 0) srow[row] = job_srpt[job_ids[row]];
}

// ---------------------------------------------------------------------------
// Transpose-convert fp32 W[K][1024] -> bf16 Wt[1024][K] (first Kuse rows).
// ---------------------------------------------------------------------------
__global__ __launch_bounds__(256) void wconv_kernel(
    const float* __restrict__ W, __hip_bfloat16* __restrict__ Wt, int K) {
  __shared__ float tile[64][65];
  const int kb = blockIdx.x * 64;
  const int nb = blockIdx.y * 64;
  const int t = threadIdx.x;
#pragma unroll
  for (int it = 0; it < 16; ++it) {
    int idx = it * 256 + t;
    int kk = idx >> 6, nn = idx & 63;
    tile[kk][nn] = W[(long)(kb + kk) * 1024 + nb + nn];
  }
  __syncthreads();
#pragma unroll
  for (int it = 0; it < 16; ++it) {
    int idx = it * 256 + t;
    int nn = idx >> 6, kk = idx & 63;
    Wt[(long)(nb + nn) * K + kb + kk] = __float2bfloat16(tile[kk][nn]);
  }
}

// ---------------------------------------------------------------------------
// C[M][N] = lrelu(A[M][K] @ Bt[N][K]^T + bias (+ rank2 srpt/pt correction))
// 128x128 tile, BK=64, 4 waves (2x2), 16x16x32 bf16 MFMA.
// ---------------------------------------------------------------------------
__global__ __launch_bounds__(256) void gemm_kernel(
    const __hip_bfloat16* __restrict__ A, const __hip_bfloat16* __restrict__ Bt,
    __hip_bfloat16* __restrict__ C, const float* __restrict__ bias, int M,
    int N, int K, int rank2, const float* __restrict__ wr0,
    const float* __restrict__ wr1, const float* __restrict__ srow,
    const float* __restrict__ ptv) {
  __shared__ __align__(16) __hip_bfloat16 As[128 * 64];
  __shared__ __align__(16) __hip_bfloat16 Bs[128 * 64];
  const int t = threadIdx.x;
  const int lane = t & 63;
  const int wid = t >> 6;
  const int wm = wid >> 1, wn = wid & 1;
  const long arow0 = (long)blockIdx.x * 128;
  const int bcol0 = blockIdx.y * 128;

  f32x4 acc[4][4] = {};

  for (int kt = 0; kt < K; kt += 64) {
#pragma unroll
    for (int it = 0; it < 4; ++it) {
      int cc = it * 256 + t;
      int r = cc >> 3, c8 = cc & 7;
      GL2LDS16(A + (arow0 + r) * (long)K + kt + c8 * 8, &As[cc * 8]);
    }
#pragma unroll
    for (int it = 0; it < 4; ++it) {
      int cc = it * 256 + t;
      int r = cc >> 3, c8 = cc & 7;
      GL2LDS16(Bt + (long)(bcol0 + r) * (long)K + kt + c8 * 8, &Bs[cc * 8]);
    }
    __syncthreads();
#pragma unroll
    for (int ks = 0; ks < 2; ++ks) {
      const int kofs = ks * 32 + (lane >> 4) * 8;
      short8 af[4], bfr[4];
#pragma unroll
      for (int i = 0; i < 4; ++i) {
        int r = wm * 64 + i * 16 + (lane & 15);
        af[i] = *(const short8*)&As[r * 64 + kofs];
      }
#pragma unroll
      for (int j = 0; j < 4; ++j) {
        int r = wn * 64 + j * 16 + (lane & 15);
        bfr[j] = *(const short8*)&Bs[r * 64 + kofs];
      }
#pragma unroll
      for (int i = 0; i < 4; ++i)
#pragma unroll
        for (int j = 0; j < 4; ++j)
          acc[i][j] = __builtin_amdgcn_mfma_f32_16x16x32_bf16(af[i], bfr[j],
                                                              acc[i][j], 0, 0, 0);
    }
    __syncthreads();
  }

#pragma unroll
  for (int j = 0; j < 4; ++j) {
    const int c = bcol0 + wn * 64 + j * 16 + (lane & 15);
    const float bia = bias[c];
    float wa = 0.f, wb = 0.f;
    if (rank2) {
      wa = wr0[c];
      wb = wr1[c];
    }
#pragma unroll
    for (int i = 0; i < 4; ++i) {
      const long rb = arow0 + wm * 64 + i * 16 + ((lane >> 4) << 2);
#pragma unroll
      for (int g = 0; g < 4; ++g) {
        const long r = rb + g;
        float v = acc[i][j][g] + bia;
        if (rank2) v += srow[r] * wa + ptv[r] * wb;
        v = v > 0.f ? v : 0.01f * v;
        C[r * N + c] = __float2bfloat16(v);
      }
    }
  }
}

// ---------------------------------------------------------------------------
// score[r] = h[r][:] . W3 + b3   (fp32 accumulate, one wave per row)
// ---------------------------------------------------------------------------
__device__ inline float bf2f(unsigned short u) {
  unsigned int x = ((unsigned int)u) << 16;
  float f;
  __builtin_memcpy(&f, &x, 4);
  return f;
}

__global__ __launch_bounds__(256) void score_kernel(
    const __hip_bfloat16* __restrict__ h, const float* __restrict__ W3,
    const float* __restrict__ b3, float* __restrict__ score) {
  const int lane = threadIdx.x & 63;
  const int w = threadIdx.x >> 6;
  const long r = (long)blockIdx.x * 4 + w;
  const __hip_bfloat16* hr = h + r * 1024 + lane * 16;
  float s = 0.f;
#pragma unroll
  for (int u2 = 0; u2 < 2; ++u2) {
    short8 v = *(const short8*)(hr + u2 * 8);
#pragma unroll
    for (int e = 0; e < 8; ++e) {
      int k = lane * 16 + u2 * 8 + e;
      s += bf2f(((unsigned short)v[e])) * W3[k];
    }
  }
#pragma unroll
  for (int off = 32; off; off >>= 1) s += __shfl_down(s, off);
  if (lane == 0) score[r] = s + b3[0];
}

// ---------------------------------------------------------------------------
// softmax + argmax reductions
// ---------------------------------------------------------------------------
__global__ __launch_bounds__(256) void redmax_kernel(
    const float* __restrict__ score, float* __restrict__ pmax,
    int* __restrict__ pidx) {
  const int t = threadIdx.x, b = blockIdx.x;
  float m = -1e30f;
  int mi = 0;
#pragma unroll
  for (int u = 0; u < 2; ++u) {
    int i = b * 512 + u * 256 + t;
    float v = score[i];
    if (v > m) {
      m = v;
      mi = i;
    }
  }
  __shared__ float sm[4];
  __shared__ int si[4];
#pragma unroll
  for (int off = 32; off; off >>= 1) {
    float om = __shfl_down(m, off);
    int oi = __shfl_down(mi, off);
    if (om > m || (om == m && oi < mi)) {
      m = om;
      mi = oi;
    }
  }
  const int lane = t & 63, w = t >> 6;
  if (lane == 0) {
    sm[w] = m;
    si[w] = mi;
  }
  __syncthreads();
  if (t == 0) {
    for (int w2 = 1; w2 < 4; ++w2)
      if (sm[w2] > m || (sm[w2] == m && si[w2] < mi)) {
        m = sm[w2];
        mi = si[w2];
      }
    pmax[b] = m;
    pidx[b] = mi;
  }
}

__global__ __launch_bounds__(64) void finmax_kernel(
    const float* __restrict__ pmax, const int* __restrict__ pidx,
    float* __restrict__ gscal, float* __restrict__ out_idx) {
  const int t = threadIdx.x;
  float m = pmax[t];
  int mi = pidx[t];
#pragma unroll
  for (int off = 32; off; off >>= 1) {
    float om = __shfl_down(m, off);
    int oi = __shfl_down(mi, off);
    if (om > m || (om == m && oi < mi)) {
      m = om;
      mi = oi;
    }
  }
  if (t == 0) {
    gscal[0] = m;
    out_idx[0] = (float)mi;
  }
}

__global__ __launch_bounds__(256) void expsum_kernel(
    const float* __restrict__ score, const float* __restrict__ gscal,
    float* __restrict__ e, float* __restrict__ psum) {
  const int t = threadIdx.x, b = blockIdx.x;
  const float gmax = gscal[0];
  float s = 0.f;
#pragma unroll
  for (int u = 0; u < 2; ++u) {
    int i = b * 512 + u * 256 + t;
    float v = expf(score[i] - gmax);
    e[i] = v;
    s += v;
  }
#pragma unroll
  for (int off = 32; off; off >>= 1) s += __shfl_down(s, off);
  __shared__ float sm[4];
  const int lane = t & 63, w = t >> 6;
  if (lane == 0) sm[w] = s;
  __syncthreads();
  if (t == 0) psum[b] = sm[0] + sm[1] + sm[2] + sm[3];
}

__global__ __launch_bounds__(64) void finsum_kernel(const float* __restrict__ psum,
                                                    float* __restrict__ gscal) {
  float s = psum[threadIdx.x];
#pragma unroll
  for (int off = 32; off; off >>= 1) s += __shfl_down(s, off);
  if (threadIdx.x == 0) gscal[1] = 1.0f / s;
}

__global__ __launch_bounds__(256) void scale_kernel(float* __restrict__ e,
                                                    const float* __restrict__ gscal) {
  const float inv = gscal[1];
  const int i = blockIdx.x * 512 + threadIdx.x;
  e[i] *= inv;
  e[i + 256] *= inv;
}

// ---------------------------------------------------------------------------
extern "C" void kernel_launch(void* const* d_in, const int* in_sizes, int n_in,
                              void* d_out, int out_size, void* d_ws,
                              size_t ws_size, hipStream_t stream) {
  const float* x_m = (const float*)d_in[0];
  const float* x_op = (const float*)d_in[1];
  const float* job_srpt = (const float*)d_in[2];
  const float* pt = (const float*)d_in[3];
  const float* W0 = (const float*)d_in[4];
  const float* b0 = (const float*)d_in[5];
  const float* W1 = (const float*)d_in[6];
  const float* b1 = (const float*)d_in[7];
  const float* W2 = (const float*)d_in[8];
  const float* b2 = (const float*)d_in[9];
  const float* W3 = (const float*)d_in[10];
  const float* b3 = (const float*)d_in[11];
  const int* m_ids = (const int*)d_in[12];
  const int* op_idx = (const int*)d_in[13];
  const int* job_ids = (const int*)d_in[14];

  const int M = 32768;

  char* p = (char*)d_ws;
  __hip_bfloat16* feat = (__hip_bfloat16*)p;            p += (size_t)M * 2048 * 2;
  __hip_bfloat16* hA = (__hip_bfloat16*)p;              p += (size_t)M * 1024 * 2;
  __hip_bfloat16* hB = (__hip_bfloat16*)p;              p += (size_t)M * 1024 * 2;
  __hip_bfloat16* Wt0 = (__hip_bfloat16*)p;             p += (size_t)1024 * 2048 * 2;
  __hip_bfloat16* Wt1 = (__hip_bfloat16*)p;             p += (size_t)1024 * 1024 * 2;
  __hip_bfloat16* Wt2 = (__hip_bfloat16*)p;             p += (size_t)1024 * 1024 * 2;
  float* srow = (float*)p;                              p += (size_t)M * 4;
  float* score = (float*)p;                             p += (size_t)M * 4;
  float* pmax = (float*)p;                              p += 256;
  int* pidx = (int*)p;                                  p += 256;
  float* psum = (float*)p;                              p += 256;
  float* gscal = (float*)p;                             p += 256;

  float* probs = (float*)d_out;
  float* out_idx = probs + M;

  feat_kernel<<<M, 256, 0, stream>>>(x_m, x_op, job_srpt, m_ids, op_idx,
                                     job_ids, feat, srow);
  wconv_kernel<<<dim3(32, 16), 256, 0, stream>>>(W0, Wt0, 2048);
  wconv_kernel<<<dim3(16, 16), 256, 0, stream>>>(W1, Wt1, 1024);
  wconv_kernel<<<dim3(16, 16), 256, 0, stream>>>(W2, Wt2, 1024);

  gemm_kernel<<<dim3(256, 8), 256, 0, stream>>>(
      feat, Wt0, hA, b0, M, 1024, 2048, 1, W0 + (size_t)2048 * 1024,
      W0 + (size_t)2049 * 1024, srow, pt);
  gemm_kernel<<<dim3(256, 8), 256, 0, stream>>>(hA, Wt1, hB, b1, M, 1024, 1024,
                                                0, nullptr, nullptr, nullptr,
                                                nullptr);
  gemm_kernel<<<dim3(256, 8), 256, 0, stream>>>(hB, Wt2, hA, b2, M, 1024, 1024,
                                                0, nullptr, nullptr, nullptr,
                                                nullptr);

  score_kernel<<<M / 4, 256, 0, stream>>>(hA, W3, b3, score);
  redmax_kernel<<<64, 256, 0, stream>>>(score, pmax, pidx);
  finmax_kernel<<<1, 64, 0, stream>>>(pmax, pidx, gscal, out_idx);
  expsum_kernel<<<64, 256, 0, stream>>>(score, gscal, probs, psum);
  finsum_kernel<<<1, 64, 0, stream>>>(psum, gscal);
  scale_kernel<<<64, 256, 0, stream>>>(probs, gscal);
}

// Round 2
// 532.747 us; speedup vs baseline: 1.0917x; 1.0917x over previous
//
#include <hip/hip_runtime.h>
#include <hip/hip_bf16.h>

typedef __attribute__((ext_vector_type(8))) short short8;
typedef __attribute__((ext_vector_type(4))) float f32x4;

#define GL2LDS16(g, l)                                                         \
  __builtin_amdgcn_global_load_lds(                                            \
      (const __attribute__((address_space(1))) unsigned int*)(g),              \
      (__attribute__((address_space(3))) unsigned int*)(l), 16, 0, 0)

// ---------------------------------------------------------------------------
// feat[row][0:1024] = x_m[m_ids[row]]; feat[row][1024:2048] = x_op[op_idx[row]]
// (bf16). Also srow[row] = job_srpt[job_ids[row]] (fp32).
// ---------------------------------------------------------------------------
__global__ __launch_bounds__(256) void feat_kernel(
    const float* __restrict__ x_m, const float* __restrict__ x_op,
    const float* __restrict__ job_srpt, const int* __restrict__ m_ids,
    const int* __restrict__ op_idx, const int* __restrict__ job_ids,
    __hip_bfloat16* __restrict__ feat, float* __restrict__ srow) {
  const int row = blockIdx.x;
  const int t = threadIdx.x;
  const int j0 = t * 8;
  const float* src;
  if (j0 < 1024)
    src = x_m + (long)m_ids[row] * 1024 + j0;
  else
    src = x_op + (long)op_idx[row] * 1024 + (j0 - 1024);
  float4 v0 = *(const float4*)src;
  float4 v1 = *(const float4*)(src + 4);
  union {
    __hip_bfloat16 h[8];
    int4 i4;
  } u;
  u.h[0] = __float2bfloat16(v0.x);
  u.h[1] = __float2bfloat16(v0.y);
  u.h[2] = __float2bfloat16(v0.z);
  u.h[3] = __float2bfloat16(v0.w);
  u.h[4] = __float2bfloat16(v1.x);
  u.h[5] = __float2bfloat16(v1.y);
  u.h[6] = __float2bfloat16(v1.z);
  u.h[7] = __float2bfloat16(v1.w);
  *(int4*)&feat[(long)row * 2048 + j0] = u.i4;
  if (t == 0) srow[row] = job_srpt[job_ids[row]];
}

// ---------------------------------------------------------------------------
// Transpose-convert fp32 W[K][1024] -> bf16 Wt[1024][K].
// ---------------------------------------------------------------------------
__global__ __launch_bounds__(256) void wconv_kernel(
    const float* __restrict__ W, __hip_bfloat16* __restrict__ Wt, int K) {
  __shared__ float tile[64][65];
  const int kb = blockIdx.x * 64;
  const int nb = blockIdx.y * 64;
  const int t = threadIdx.x;
#pragma unroll
  for (int it = 0; it < 16; ++it) {
    int idx = it * 256 + t;
    int kk = idx >> 6, nn = idx & 63;
    tile[kk][nn] = W[(long)(kb + kk) * 1024 + nb + nn];
  }
  __syncthreads();
#pragma unroll
  for (int it = 0; it < 16; ++it) {
    int idx = it * 256 + t;
    int nn = idx >> 6, kk = idx & 63;
    Wt[(long)(nb + nn) * K + kb + kk] = __float2bfloat16(tile[kk][nn]);
  }
}

// ---------------------------------------------------------------------------
// C[M][N] = lrelu(A[M][K] @ Bt[N][K]^T + bias (+ rank2 srpt/pt correction))
// 128x128 tile, BK=64, 4 waves (2x2), 16x16x32 bf16 MFMA.
// LDS tiles XOR-swizzled (16B-chunk granularity): logical (row, chunk c8)
// lives at physical chunk c8 ^ (row&7). global_load_lds keeps a LINEAR dest;
// the permutation is applied on the global SOURCE address (rule #21), and the
// same XOR on the ds_read side.
// If fuseW3: skip the C write; instead accumulate score[r] += lrelu(.)*W3[c]
// via 16-lane shfl_xor reduce + atomicAdd.
// ---------------------------------------------------------------------------
__global__ __launch_bounds__(256) void gemm_kernel(
    const __hip_bfloat16* __restrict__ A, const __hip_bfloat16* __restrict__ Bt,
    __hip_bfloat16* __restrict__ C, const float* __restrict__ bias, int M,
    int N, int K, int rank2, const float* __restrict__ wr0,
    const float* __restrict__ wr1, const float* __restrict__ srow,
    const float* __restrict__ ptv, int fuseW3,
    const float* __restrict__ W3, float* __restrict__ scoreOut) {
  __shared__ __align__(16) __hip_bfloat16 As[128 * 64];
  __shared__ __align__(16) __hip_bfloat16 Bs[128 * 64];
  const int t = threadIdx.x;
  const int lane = t & 63;
  const int wid = t >> 6;
  const int wm = wid >> 1, wn = wid & 1;
  const long arow0 = (long)blockIdx.x * 128;
  const int bcol0 = blockIdx.y * 128;

  f32x4 acc[4][4] = {};

  for (int kt = 0; kt < K; kt += 64) {
#pragma unroll
    for (int it = 0; it < 4; ++it) {
      int cc = it * 256 + t;
      int r = cc >> 3, c8 = (cc & 7) ^ (r & 7);   // pre-swizzled source col
      GL2LDS16(A + (arow0 + r) * (long)K + kt + c8 * 8, &As[cc * 8]);
    }
#pragma unroll
    for (int it = 0; it < 4; ++it) {
      int cc = it * 256 + t;
      int r = cc >> 3, c8 = (cc & 7) ^ (r & 7);
      GL2LDS16(Bt + (long)(bcol0 + r) * (long)K + kt + c8 * 8, &Bs[cc * 8]);
    }
    __syncthreads();
#pragma unroll
    for (int ks = 0; ks < 2; ++ks) {
      const int kofs = ks * 32 + (lane >> 4) * 8;
      const int ko = kofs ^ ((lane & 7) << 3);    // read-side XOR (r&7==lane&7)
      short8 af[4], bfr[4];
#pragma unroll
      for (int i = 0; i < 4; ++i) {
        int r = wm * 64 + i * 16 + (lane & 15);
        af[i] = *(const short8*)&As[r * 64 + ko];
      }
#pragma unroll
      for (int j = 0; j < 4; ++j) {
        int r = wn * 64 + j * 16 + (lane & 15);
        bfr[j] = *(const short8*)&Bs[r * 64 + ko];
      }
#pragma unroll
      for (int i = 0; i < 4; ++i)
#pragma unroll
        for (int j = 0; j < 4; ++j)
          acc[i][j] = __builtin_amdgcn_mfma_f32_16x16x32_bf16(af[i], bfr[j],
                                                              acc[i][j], 0, 0, 0);
    }
    __syncthreads();
  }

  if (!fuseW3) {
#pragma unroll
    for (int j = 0; j < 4; ++j) {
      const int c = bcol0 + wn * 64 + j * 16 + (lane & 15);
      const float bia = bias[c];
      float wa = 0.f, wb = 0.f;
      if (rank2) {
        wa = wr0[c];
        wb = wr1[c];
      }
#pragma unroll
      for (int i = 0; i < 4; ++i) {
        const long rb = arow0 + wm * 64 + i * 16 + ((lane >> 4) << 2);
#pragma unroll
        for (int g = 0; g < 4; ++g) {
          const long r = rb + g;
          float v = acc[i][j][g] + bia;
          if (rank2) v += srow[r] * wa + ptv[r] * wb;
          v = v > 0.f ? v : 0.01f * v;
          C[r * N + c] = __float2bfloat16(v);
        }
      }
    }
  } else {
    float bia[4], w3[4];
#pragma unroll
    for (int j = 0; j < 4; ++j) {
      const int c = bcol0 + wn * 64 + j * 16 + (lane & 15);
      bia[j] = bias[c];
      w3[j] = W3[c];
    }
#pragma unroll
    for (int i = 0; i < 4; ++i) {
#pragma unroll
      for (int g = 0; g < 4; ++g) {
        float ps = 0.f;
#pragma unroll
        for (int j = 0; j < 4; ++j) {
          float v = acc[i][j][g] + bia[j];
          v = v > 0.f ? v : 0.01f * v;
          ps += v * w3[j];
        }
        ps += __shfl_xor(ps, 1);
        ps += __shfl_xor(ps, 2);
        ps += __shfl_xor(ps, 4);
        ps += __shfl_xor(ps, 8);
        if ((lane & 15) == 0) {
          const long r = arow0 + wm * 64 + i * 16 + ((lane >> 4) << 2) + g;
          atomicAdd(&scoreOut[r], ps);
        }
      }
    }
  }
}

// ---------------------------------------------------------------------------
// softmax + argmax reductions (b3 is a constant shift -> cancels in softmax
// and does not change argmax; omitted).
// ---------------------------------------------------------------------------
__global__ __launch_bounds__(256) void redmax_kernel(
    const float* __restrict__ score, float* __restrict__ pmax,
    int* __restrict__ pidx) {
  const int t = threadIdx.x, b = blockIdx.x;
  float m = -1e30f;
  int mi = 0;
#pragma unroll
  for (int u = 0; u < 2; ++u) {
    int i = b * 512 + u * 256 + t;
    float v = score[i];
    if (v > m) {
      m = v;
      mi = i;
    }
  }
  __shared__ float sm[4];
  __shared__ int si[4];
#pragma unroll
  for (int off = 32; off; off >>= 1) {
    float om = __shfl_down(m, off);
    int oi = __shfl_down(mi, off);
    if (om > m || (om == m && oi < mi)) {
      m = om;
      mi = oi;
    }
  }
  const int lane = t & 63, w = t >> 6;
  if (lane == 0) {
    sm[w] = m;
    si[w] = mi;
  }
  __syncthreads();
  if (t == 0) {
    for (int w2 = 1; w2 < 4; ++w2)
      if (sm[w2] > m || (sm[w2] == m && si[w2] < mi)) {
        m = sm[w2];
        mi = si[w2];
      }
    pmax[b] = m;
    pidx[b] = mi;
  }
}

__global__ __launch_bounds__(64) void finmax_kernel(
    const float* __restrict__ pmax, const int* __restrict__ pidx,
    float* __restrict__ gscal, float* __restrict__ out_idx) {
  const int t = threadIdx.x;
  float m = pmax[t];
  int mi = pidx[t];
#pragma unroll
  for (int off = 32; off; off >>= 1) {
    float om = __shfl_down(m, off);
    int oi = __shfl_down(mi, off);
    if (om > m || (om == m && oi < mi)) {
      m = om;
      mi = oi;
    }
  }
  if (t == 0) {
    gscal[0] = m;
    out_idx[0] = (float)mi;
  }
}

__global__ __launch_bounds__(256) void expsum_kernel(
    const float* __restrict__ score, const float* __restrict__ gscal,
    float* __restrict__ e, float* __restrict__ psum) {
  const int t = threadIdx.x, b = blockIdx.x;
  const float gmax = gscal[0];
  float s = 0.f;
#pragma unroll
  for (int u = 0; u < 2; ++u) {
    int i = b * 512 + u * 256 + t;
    float v = expf(score[i] - gmax);
    e[i] = v;
    s += v;
  }
#pragma unroll
  for (int off = 32; off; off >>= 1) s += __shfl_down(s, off);
  __shared__ float sm[4];
  const int lane = t & 63, w = t >> 6;
  if (lane == 0) sm[w] = s;
  __syncthreads();
  if (t == 0) psum[b] = sm[0] + sm[1] + sm[2] + sm[3];
}

__global__ __launch_bounds__(64) void finsum_kernel(const float* __restrict__ psum,
                                                    float* __restrict__ gscal) {
  float s = psum[threadIdx.x];
#pragma unroll
  for (int off = 32; off; off >>= 1) s += __shfl_down(s, off);
  if (threadIdx.x == 0) gscal[1] = 1.0f / s;
}

__global__ __launch_bounds__(256) void scale_kernel(float* __restrict__ e,
                                                    const float* __restrict__ gscal) {
  const float inv = gscal[1];
  const int i = blockIdx.x * 512 + threadIdx.x;
  e[i] *= inv;
  e[i + 256] *= inv;
}

// ---------------------------------------------------------------------------
extern "C" void kernel_launch(void* const* d_in, const int* in_sizes, int n_in,
                              void* d_out, int out_size, void* d_ws,
                              size_t ws_size, hipStream_t stream) {
  const float* x_m = (const float*)d_in[0];
  const float* x_op = (const float*)d_in[1];
  const float* job_srpt = (const float*)d_in[2];
  const float* pt = (const float*)d_in[3];
  const float* W0 = (const float*)d_in[4];
  const float* b0 = (const float*)d_in[5];
  const float* W1 = (const float*)d_in[6];
  const float* b1 = (const float*)d_in[7];
  const float* W2 = (const float*)d_in[8];
  const float* b2 = (const float*)d_in[9];
  const float* W3 = (const float*)d_in[10];
  const int* m_ids = (const int*)d_in[12];
  const int* op_idx = (const int*)d_in[13];
  const int* job_ids = (const int*)d_in[14];

  const int M = 32768;

  char* p = (char*)d_ws;
  __hip_bfloat16* feat = (__hip_bfloat16*)p;            p += (size_t)M * 2048 * 2;
  __hip_bfloat16* hA = (__hip_bfloat16*)p;              p += (size_t)M * 1024 * 2;
  __hip_bfloat16* hB = (__hip_bfloat16*)p;              p += (size_t)M * 1024 * 2;
  __hip_bfloat16* Wt0 = (__hip_bfloat16*)p;             p += (size_t)1024 * 2048 * 2;
  __hip_bfloat16* Wt1 = (__hip_bfloat16*)p;             p += (size_t)1024 * 1024 * 2;
  __hip_bfloat16* Wt2 = (__hip_bfloat16*)p;             p += (size_t)1024 * 1024 * 2;
  float* srow = (float*)p;                              p += (size_t)M * 4;
  float* score = (float*)p;                             p += (size_t)M * 4;
  float* pmax = (float*)p;                              p += 256;
  int* pidx = (int*)p;                                  p += 256;
  float* psum = (float*)p;                              p += 256;
  float* gscal = (float*)p;                             p += 256;

  float* probs = (float*)d_out;
  float* out_idx = probs + M;

  feat_kernel<<<M, 256, 0, stream>>>(x_m, x_op, job_srpt, m_ids, op_idx,
                                     job_ids, feat, srow);
  wconv_kernel<<<dim3(32, 16), 256, 0, stream>>>(W0, Wt0, 2048);
  wconv_kernel<<<dim3(16, 16), 256, 0, stream>>>(W1, Wt1, 1024);
  wconv_kernel<<<dim3(16, 16), 256, 0, stream>>>(W2, Wt2, 1024);
  hipMemsetAsync(score, 0, (size_t)M * 4, stream);

  gemm_kernel<<<dim3(256, 8), 256, 0, stream>>>(
      feat, Wt0, hA, b0, M, 1024, 2048, 1, W0 + (size_t)2048 * 1024,
      W0 + (size_t)2049 * 1024, srow, pt, 0, nullptr, nullptr);
  gemm_kernel<<<dim3(256, 8), 256, 0, stream>>>(hA, Wt1, hB, b1, M, 1024, 1024,
                                                0, nullptr, nullptr, nullptr,
                                                nullptr, 0, nullptr, nullptr);
  gemm_kernel<<<dim3(256, 8), 256, 0, stream>>>(hB, Wt2, nullptr, b2, M, 1024,
                                                1024, 0, nullptr, nullptr,
                                                nullptr, nullptr, 1, W3, score);

  redmax_kernel<<<64, 256, 0, stream>>>(score, pmax, pidx);
  finmax_kernel<<<1, 64, 0, stream>>>(pmax, pidx, gscal, out_idx);
  expsum_kernel<<<64, 256, 0, stream>>>(score, gscal, probs, psum);
  finsum_kernel<<<1, 64, 0, stream>>>(psum, gscal);
  scale_kernel<<<64, 256, 0, stream>>>(probs, gscal);
}

// Round 3
// 457.022 us; speedup vs baseline: 1.2726x; 1.1657x over previous
//
#include <hip/hip_runtime.h>
#include <hip/hip_bf16.h>

typedef __attribute__((ext_vector_type(8))) short short8;
typedef __attribute__((ext_vector_type(4))) float f32x4;

#define GL2LDS16(g, l)                                                         \
  __builtin_amdgcn_global_load_lds(                                            \
      (const __attribute__((address_space(1))) unsigned int*)(g),              \
      (__attribute__((address_space(3))) unsigned int*)(l), 16, 0, 0)

// ---------------------------------------------------------------------------
// feat[row][0:1024] = x_m[m_ids[row]]; feat[row][1024:2048] = x_op[op_idx[row]]
// (bf16). Also srow[row] = job_srpt[job_ids[row]] (fp32).
// ---------------------------------------------------------------------------
__global__ __launch_bounds__(256) void feat_kernel(
    const float* __restrict__ x_m, const float* __restrict__ x_op,
    const float* __restrict__ job_srpt, const int* __restrict__ m_ids,
    const int* __restrict__ op_idx, const int* __restrict__ job_ids,
    __hip_bfloat16* __restrict__ feat, float* __restrict__ srow) {
  const int row = blockIdx.x;
  const int t = threadIdx.x;
  const int j0 = t * 8;
  const float* src;
  if (j0 < 1024)
    src = x_m + (long)m_ids[row] * 1024 + j0;
  else
    src = x_op + (long)op_idx[row] * 1024 + (j0 - 1024);
  float4 v0 = *(const float4*)src;
  float4 v1 = *(const float4*)(src + 4);
  union {
    __hip_bfloat16 h[8];
    int4 i4;
  } u;
  u.h[0] = __float2bfloat16(v0.x);
  u.h[1] = __float2bfloat16(v0.y);
  u.h[2] = __float2bfloat16(v0.z);
  u.h[3] = __float2bfloat16(v0.w);
  u.h[4] = __float2bfloat16(v1.x);
  u.h[5] = __float2bfloat16(v1.y);
  u.h[6] = __float2bfloat16(v1.z);
  u.h[7] = __float2bfloat16(v1.w);
  *(int4*)&feat[(long)row * 2048 + j0] = u.i4;
  if (t == 0) srow[row] = job_srpt[job_ids[row]];
}

// ---------------------------------------------------------------------------
// Transpose-convert fp32 W[K][1024] -> bf16 Wt[1024][K].
// ---------------------------------------------------------------------------
__global__ __launch_bounds__(256) void wconv_kernel(
    const float* __restrict__ W, __hip_bfloat16* __restrict__ Wt, int K) {
  __shared__ float tile[64][65];
  const int kb = blockIdx.x * 64;
  const int nb = blockIdx.y * 64;
  const int t = threadIdx.x;
#pragma unroll
  for (int it = 0; it < 16; ++it) {
    int idx = it * 256 + t;
    int kk = idx >> 6, nn = idx & 63;
    tile[kk][nn] = W[(long)(kb + kk) * 1024 + nb + nn];
  }
  __syncthreads();
#pragma unroll
  for (int it = 0; it < 16; ++it) {
    int idx = it * 256 + t;
    int nn = idx >> 6, kk = idx & 63;
    Wt[(long)(nb + nn) * K + kb + kk] = __float2bfloat16(tile[kk][nn]);
  }
}

// ---------------------------------------------------------------------------
// C[M][N] = lrelu(A[M][K] @ Bt[N][K]^T + bias (+ rank2 srpt/pt correction))
// 256x256 tile, BK=64, 8 waves (2Mx4N), double-buffered LDS, counted-vmcnt
// prefetch pipeline: next tile's 8 global_load_lds stay in flight across the
// compute phase (s_waitcnt vmcnt(8), raw s_barrier). LDS 16B-chunk XOR
// swizzle (source-side pre-swizzle + read-side XOR, rule #21).
// If fuseW3: accumulate score[r] += lrelu(.)*W3[c] via shfl_xor + atomicAdd.
// ---------------------------------------------------------------------------
__global__ __launch_bounds__(512, 2) void gemm_kernel(
    const __hip_bfloat16* __restrict__ A, const __hip_bfloat16* __restrict__ Bt,
    __hip_bfloat16* __restrict__ C, const float* __restrict__ bias, int M,
    int N, int K, int rank2, const float* __restrict__ wr0,
    const float* __restrict__ wr1, const float* __restrict__ srow,
    const float* __restrict__ ptv, int fuseW3,
    const float* __restrict__ W3, float* __restrict__ scoreOut) {
  __shared__ __align__(16) __hip_bfloat16 As[2][256 * 64];
  __shared__ __align__(16) __hip_bfloat16 Bs[2][256 * 64];
  const int t = threadIdx.x;
  const int lane = t & 63;
  const int wid = t >> 6;   // 0..7
  const int wm = wid >> 2;  // 0..1  (M half: 128 rows)
  const int wn = wid & 3;   // 0..3  (N quarter: 64 cols)
  const long arow0 = (long)blockIdx.x * 256;
  const int bcol0 = blockIdx.y * 256;
  const int NT = K >> 6;

  f32x4 acc[8][4] = {};

  auto stage = [&](int buf, int kt) {
#pragma unroll
    for (int it = 0; it < 4; ++it) {
      int cc = it * 512 + t;
      int r = cc >> 3, c8 = (cc & 7) ^ (r & 7);  // pre-swizzled source chunk
      GL2LDS16(A + (arow0 + r) * (long)K + kt * 64 + c8 * 8, &As[buf][cc * 8]);
    }
#pragma unroll
    for (int it = 0; it < 4; ++it) {
      int cc = it * 512 + t;
      int r = cc >> 3, c8 = (cc & 7) ^ (r & 7);
      GL2LDS16(Bt + (long)(bcol0 + r) * (long)K + kt * 64 + c8 * 8,
               &Bs[buf][cc * 8]);
    }
  };

  stage(0, 0);

  for (int kt = 0; kt < NT; ++kt) {
    const int cur = kt & 1;
    if (kt + 1 < NT) {
      stage(cur ^ 1, kt + 1);  // 8 loads in flight across compute phase
      asm volatile("s_waitcnt vmcnt(8)" ::: "memory");
    } else {
      asm volatile("s_waitcnt vmcnt(0)" ::: "memory");
    }
    __builtin_amdgcn_s_barrier();
    asm volatile("" ::: "memory");

#pragma unroll
    for (int ks = 0; ks < 2; ++ks) {
      const int ko = (ks * 32 + ((lane >> 4) << 3)) ^ ((lane & 7) << 3);
      short8 af[8], bfr[4];
#pragma unroll
      for (int i = 0; i < 8; ++i)
        af[i] =
            *(const short8*)&As[cur][(wm * 128 + i * 16 + (lane & 15)) * 64 + ko];
#pragma unroll
      for (int j = 0; j < 4; ++j)
        bfr[j] =
            *(const short8*)&Bs[cur][(wn * 64 + j * 16 + (lane & 15)) * 64 + ko];
#pragma unroll
      for (int i = 0; i < 8; ++i)
#pragma unroll
        for (int j = 0; j < 4; ++j)
          acc[i][j] = __builtin_amdgcn_mfma_f32_16x16x32_bf16(af[i], bfr[j],
                                                              acc[i][j], 0, 0, 0);
    }

    asm volatile("s_waitcnt lgkmcnt(0)" ::: "memory");
    __builtin_amdgcn_s_barrier();
    asm volatile("" ::: "memory");
  }

  if (!fuseW3) {
#pragma unroll
    for (int j = 0; j < 4; ++j) {
      const int c = bcol0 + wn * 64 + j * 16 + (lane & 15);
      const float bia = bias[c];
      float wa = 0.f, wb = 0.f;
      if (rank2) {
        wa = wr0[c];
        wb = wr1[c];
      }
#pragma unroll
      for (int i = 0; i < 8; ++i) {
        const long rb = arow0 + wm * 128 + i * 16 + ((lane >> 4) << 2);
#pragma unroll
        for (int g = 0; g < 4; ++g) {
          const long r = rb + g;
          float v = acc[i][j][g] + bia;
          if (rank2) v += srow[r] * wa + ptv[r] * wb;
          v = v > 0.f ? v : 0.01f * v;
          C[r * N + c] = __float2bfloat16(v);
        }
      }
    }
  } else {
    float bia[4], w3v[4];
#pragma unroll
    for (int j = 0; j < 4; ++j) {
      const int c = bcol0 + wn * 64 + j * 16 + (lane & 15);
      bia[j] = bias[c];
      w3v[j] = W3[c];
    }
#pragma unroll
    for (int i = 0; i < 8; ++i) {
#pragma unroll
      for (int g = 0; g < 4; ++g) {
        float ps = 0.f;
#pragma unroll
        for (int j = 0; j < 4; ++j) {
          float v = acc[i][j][g] + bia[j];
          v = v > 0.f ? v : 0.01f * v;
          ps += v * w3v[j];
        }
        ps += __shfl_xor(ps, 1);
        ps += __shfl_xor(ps, 2);
        ps += __shfl_xor(ps, 4);
        ps += __shfl_xor(ps, 8);
        if ((lane & 15) == 0) {
          const long r = arow0 + wm * 128 + i * 16 + ((lane >> 4) << 2) + g;
          atomicAdd(&scoreOut[r], ps);
        }
      }
    }
  }
}

// ---------------------------------------------------------------------------
// softmax + argmax reductions (b3 is a constant shift -> cancels in softmax
// and does not change argmax; omitted).
// ---------------------------------------------------------------------------
__global__ __launch_bounds__(256) void redmax_kernel(
    const float* __restrict__ score, float* __restrict__ pmax,
    int* __restrict__ pidx) {
  const int t = threadIdx.x, b = blockIdx.x;
  float m = -1e30f;
  int mi = 0;
#pragma unroll
  for (int u = 0; u < 2; ++u) {
    int i = b * 512 + u * 256 + t;
    float v = score[i];
    if (v > m) {
      m = v;
      mi = i;
    }
  }
  __shared__ float sm[4];
  __shared__ int si[4];
#pragma unroll
  for (int off = 32; off; off >>= 1) {
    float om = __shfl_down(m, off);
    int oi = __shfl_down(mi, off);
    if (om > m || (om == m && oi < mi)) {
      m = om;
      mi = oi;
    }
  }
  const int lane = t & 63, w = t >> 6;
  if (lane == 0) {
    sm[w] = m;
    si[w] = mi;
  }
  __syncthreads();
  if (t == 0) {
    for (int w2 = 1; w2 < 4; ++w2)
      if (sm[w2] > m || (sm[w2] == m && si[w2] < mi)) {
        m = sm[w2];
        mi = si[w2];
      }
    pmax[b] = m;
    pidx[b] = mi;
  }
}

__global__ __launch_bounds__(64) void finmax_kernel(
    const float* __restrict__ pmax, const int* __restrict__ pidx,
    float* __restrict__ gscal, float* __restrict__ out_idx) {
  const int t = threadIdx.x;
  float m = pmax[t];
  int mi = pidx[t];
#pragma unroll
  for (int off = 32; off; off >>= 1) {
    float om = __shfl_down(m, off);
    int oi = __shfl_down(mi, off);
    if (om > m || (om == m && oi < mi)) {
      m = om;
      mi = oi;
    }
  }
  if (t == 0) {
    gscal[0] = m;
    out_idx[0] = (float)mi;
  }
}

__global__ __launch_bounds__(256) void expsum_kernel(
    const float* __restrict__ score, const float* __restrict__ gscal,
    float* __restrict__ e, float* __restrict__ psum) {
  const int t = threadIdx.x, b = blockIdx.x;
  const float gmax = gscal[0];
  float s = 0.f;
#pragma unroll
  for (int u = 0; u < 2; ++u) {
    int i = b * 512 + u * 256 + t;
    float v = expf(score[i] - gmax);
    e[i] = v;
    s += v;
  }
#pragma unroll
  for (int off = 32; off; off >>= 1) s += __shfl_down(s, off);
  __shared__ float sm[4];
  const int lane = t & 63, w = t >> 6;
  if (lane == 0) sm[w] = s;
  __syncthreads();
  if (t == 0) psum[b] = sm[0] + sm[1] + sm[2] + sm[3];
}

__global__ __launch_bounds__(64) void finsum_kernel(const float* __restrict__ psum,
                                                    float* __restrict__ gscal) {
  float s = psum[threadIdx.x];
#pragma unroll
  for (int off = 32; off; off >>= 1) s += __shfl_down(s, off);
  if (threadIdx.x == 0) gscal[1] = 1.0f / s;
}

__global__ __launch_bounds__(256) void scale_kernel(float* __restrict__ e,
                                                    const float* __restrict__ gscal) {
  const float inv = gscal[1];
  const int i = blockIdx.x * 512 + threadIdx.x;
  e[i] *= inv;
  e[i + 256] *= inv;
}

// ---------------------------------------------------------------------------
extern "C" void kernel_launch(void* const* d_in, const int* in_sizes, int n_in,
                              void* d_out, int out_size, void* d_ws,
                              size_t ws_size, hipStream_t stream) {
  const float* x_m = (const float*)d_in[0];
  const float* x_op = (const float*)d_in[1];
  const float* job_srpt = (const float*)d_in[2];
  const float* pt = (const float*)d_in[3];
  const float* W0 = (const float*)d_in[4];
  const float* b0 = (const float*)d_in[5];
  const float* W1 = (const float*)d_in[6];
  const float* b1 = (const float*)d_in[7];
  const float* W2 = (const float*)d_in[8];
  const float* b2 = (const float*)d_in[9];
  const float* W3 = (const float*)d_in[10];
  const int* m_ids = (const int*)d_in[12];
  const int* op_idx = (const int*)d_in[13];
  const int* job_ids = (const int*)d_in[14];

  const int M = 32768;

  char* p = (char*)d_ws;
  __hip_bfloat16* feat = (__hip_bfloat16*)p;            p += (size_t)M * 2048 * 2;
  __hip_bfloat16* hA = (__hip_bfloat16*)p;              p += (size_t)M * 1024 * 2;
  __hip_bfloat16* hB = (__hip_bfloat16*)p;              p += (size_t)M * 1024 * 2;
  __hip_bfloat16* Wt0 = (__hip_bfloat16*)p;             p += (size_t)1024 * 2048 * 2;
  __hip_bfloat16* Wt1 = (__hip_bfloat16*)p;             p += (size_t)1024 * 1024 * 2;
  __hip_bfloat16* Wt2 = (__hip_bfloat16*)p;             p += (size_t)1024 * 1024 * 2;
  float* srow = (float*)p;                              p += (size_t)M * 4;
  float* score = (float*)p;                             p += (size_t)M * 4;
  float* pmax = (float*)p;                              p += 256;
  int* pidx = (int*)p;                                  p += 256;
  float* psum = (float*)p;                              p += 256;
  float* gscal = (float*)p;                             p += 256;

  float* probs = (float*)d_out;
  float* out_idx = probs + M;

  feat_kernel<<<M, 256, 0, stream>>>(x_m, x_op, job_srpt, m_ids, op_idx,
                                     job_ids, feat, srow);
  wconv_kernel<<<dim3(32, 16), 256, 0, stream>>>(W0, Wt0, 2048);
  wconv_kernel<<<dim3(16, 16), 256, 0, stream>>>(W1, Wt1, 1024);
  wconv_kernel<<<dim3(16, 16), 256, 0, stream>>>(W2, Wt2, 1024);
  hipMemsetAsync(score, 0, (size_t)M * 4, stream);

  gemm_kernel<<<dim3(128, 4), 512, 0, stream>>>(
      feat, Wt0, hA, b0, M, 1024, 2048, 1, W0 + (size_t)2048 * 1024,
      W0 + (size_t)2049 * 1024, srow, pt, 0, nullptr, nullptr);
  gemm_kernel<<<dim3(128, 4), 512, 0, stream>>>(hA, Wt1, hB, b1, M, 1024, 1024,
                                                0, nullptr, nullptr, nullptr,
                                                nullptr, 0, nullptr, nullptr);
  gemm_kernel<<<dim3(128, 4), 512, 0, stream>>>(hB, Wt2, nullptr, b2, M, 1024,
                                                1024, 0, nullptr, nullptr,
                                                nullptr, nullptr, 1, W3, score);

  redmax_kernel<<<64, 256, 0, stream>>>(score, pmax, pidx);
  finmax_kernel<<<1, 64, 0, stream>>>(pmax, pidx, gscal, out_idx);
  expsum_kernel<<<64, 256, 0, stream>>>(score, gscal, probs, psum);
  finsum_kernel<<<1, 64, 0, stream>>>(psum, gscal);
  scale_kernel<<<64, 256, 0, stream>>>(probs, gscal);
}

// Round 4
// 439.959 us; speedup vs baseline: 1.3220x; 1.0388x over previous
//
#include <hip/hip_runtime.h>
#include <hip/hip_bf16.h>

typedef __attribute__((ext_vector_type(8))) short short8;
typedef __attribute__((ext_vector_type(4))) float f32x4;

#define GL2LDS16(g, l)                                                         \
  __builtin_amdgcn_global_load_lds(                                            \
      (const __attribute__((address_space(1))) unsigned int*)(g),              \
      (__attribute__((address_space(3))) unsigned int*)(l), 16, 0, 0)

// ---------------------------------------------------------------------------
// feat[row][0:1024] = x_m[m_ids[row]]; feat[row][1024:2048] = x_op[op_idx[row]]
// (bf16). Also srow[row] = job_srpt[job_ids[row]] (fp32).
// ---------------------------------------------------------------------------
__global__ __launch_bounds__(256) void feat_kernel(
    const float* __restrict__ x_m, const float* __restrict__ x_op,
    const float* __restrict__ job_srpt, const int* __restrict__ m_ids,
    const int* __restrict__ op_idx, const int* __restrict__ job_ids,
    __hip_bfloat16* __restrict__ feat, float* __restrict__ srow) {
  const int row = blockIdx.x;
  const int t = threadIdx.x;
  const int j0 = t * 8;
  const float* src;
  if (j0 < 1024)
    src = x_m + (long)m_ids[row] * 1024 + j0;
  else
    src = x_op + (long)op_idx[row] * 1024 + (j0 - 1024);
  float4 v0 = *(const float4*)src;
  float4 v1 = *(const float4*)(src + 4);
  union {
    __hip_bfloat16 h[8];
    int4 i4;
  } u;
  u.h[0] = __float2bfloat16(v0.x);
  u.h[1] = __float2bfloat16(v0.y);
  u.h[2] = __float2bfloat16(v0.z);
  u.h[3] = __float2bfloat16(v0.w);
  u.h[4] = __float2bfloat16(v1.x);
  u.h[5] = __float2bfloat16(v1.y);
  u.h[6] = __float2bfloat16(v1.z);
  u.h[7] = __float2bfloat16(v1.w);
  *(int4*)&feat[(long)row * 2048 + j0] = u.i4;
  if (t == 0) srow[row] = job_srpt[job_ids[row]];
}

// ---------------------------------------------------------------------------
// Transpose-convert fp32 W[K][1024] -> bf16 Wt[1024][K].
// ---------------------------------------------------------------------------
__global__ __launch_bounds__(256) void wconv_kernel(
    const float* __restrict__ W, __hip_bfloat16* __restrict__ Wt, int K) {
  __shared__ float tile[64][65];
  const int kb = blockIdx.x * 64;
  const int nb = blockIdx.y * 64;
  const int t = threadIdx.x;
#pragma unroll
  for (int it = 0; it < 16; ++it) {
    int idx = it * 256 + t;
    int kk = idx >> 6, nn = idx & 63;
    tile[kk][nn] = W[(long)(kb + kk) * 1024 + nb + nn];
  }
  __syncthreads();
#pragma unroll
  for (int it = 0; it < 16; ++it) {
    int idx = it * 256 + t;
    int nn = idx >> 6, kk = idx & 63;
    Wt[(long)(nb + nn) * K + kb + kk] = __float2bfloat16(tile[kk][nn]);
  }
}

// ---------------------------------------------------------------------------
// C[M][N] = lrelu(A[M][K] @ Bt[N][K]^T + bias (+ rank2 srpt/pt correction))
// 256x256 tile, BK=64, 8 waves (2Mx4N), double-buffered LDS.
// 8-PHASE schedule (4 phases per K-tile, 2 K-tiles per dbuf cycle):
//   phase = { stage 2 chunks of tile kt+1 ; s_waitcnt vmcnt(4) ; s_barrier ;
//             ds_read subtile ; lgkmcnt(0) ; setprio(1) 16 MFMA setprio(0) ;
//             s_barrier }
// Chunk schedule (for tile kt+1, issued during tile kt):
//   ph0: B-q0,B-q1   ph1: B-q2,B-q3   ph2: A-c0,A-c1   ph3: A-c2,A-c3
// A-chunk p = rows [32p,32p+32) U [128+32p,128+32p+32)  (matches phase reads)
// B-quarter q = cols [64q,64q+64).
// vmcnt(4) = 2 phases of slack; every chunk is confirmed >=1 barrier before
// its first read (verified for steady state, prologue, and last-tile drain
// which uses vmcnt(0)). LDS 16B-chunk XOR swizzle: source-side pre-swizzle +
// read-side XOR (both-sides, rule #21).
// If fuseW3: accumulate score[r] += lrelu(.)*W3[c] via shfl_xor + atomicAdd.
// ---------------------------------------------------------------------------
__global__ __launch_bounds__(512, 2) void gemm_kernel(
    const __hip_bfloat16* __restrict__ A, const __hip_bfloat16* __restrict__ Bt,
    __hip_bfloat16* __restrict__ C, const float* __restrict__ bias, int M,
    int N, int K, int rank2, const float* __restrict__ wr0,
    const float* __restrict__ wr1, const float* __restrict__ srow,
    const float* __restrict__ ptv, int fuseW3,
    const float* __restrict__ W3, float* __restrict__ scoreOut) {
  __shared__ __align__(16) __hip_bfloat16 As[2][256 * 64];
  __shared__ __align__(16) __hip_bfloat16 Bs[2][256 * 64];
  const int t = threadIdx.x;
  const int lane = t & 63;
  const int wid = t >> 6;   // 0..7
  const int wm = wid >> 2;  // 0..1  (M half: 128 rows)
  const int wn = wid & 3;   // 0..3  (N quarter: 64 cols)
  const long arow0 = (long)blockIdx.x * 256;
  const int bcol0 = blockIdx.y * 256;
  const int NT = K >> 6;

  // staging geometry (1 load/thread per 8KB chunk, LDS dest linear in t)
  const int sa_row = ((t >> 8) * 128) + ((t >> 3) & 31);  // + p*32
  const int sb_row = t >> 3;                              // + q*64
  const int scol = ((t & 7) ^ ((t >> 3) & 7)) * 8;        // pre-swizzled col

#define STAGE_A(buf, kt1, p)                                                   \
  GL2LDS16(A + (arow0 + sa_row + (p) * 32) * (long)K + (kt1) * 64 + scol,      \
           &As[buf][(t >> 8) * 8192 + (p) * 2048 + (t & 255) * 8])
#define STAGE_B(buf, kt1, q)                                                   \
  GL2LDS16(Bt + (long)(bcol0 + sb_row + (q) * 64) * (long)K + (kt1) * 64 + scol, \
           &Bs[buf][(q) * 4096 + t * 8])

  f32x4 acc[8][4] = {};
  short8 bfr[8];

  // prologue: stage all of tile 0 (order must match steady-state: B0..B3,A0..A3)
#pragma unroll
  for (int q = 0; q < 4; ++q) STAGE_B(0, 0, q);
#pragma unroll
  for (int p = 0; p < 4; ++p) STAGE_A(0, 0, p);

  for (int kt = 0; kt < NT; ++kt) {
    const int cur = kt & 1;
    const bool pre = (kt + 1) < NT;
#pragma unroll
    for (int p = 0; p < 4; ++p) {
      if (pre) {
        if (p == 0) { STAGE_B(cur ^ 1, kt + 1, 0); STAGE_B(cur ^ 1, kt + 1, 1); }
        if (p == 1) { STAGE_B(cur ^ 1, kt + 1, 2); STAGE_B(cur ^ 1, kt + 1, 3); }
        if (p == 2) { STAGE_A(cur ^ 1, kt + 1, 0); STAGE_A(cur ^ 1, kt + 1, 1); }
        if (p == 3) { STAGE_A(cur ^ 1, kt + 1, 2); STAGE_A(cur ^ 1, kt + 1, 3); }
        asm volatile("s_waitcnt vmcnt(4)" ::: "memory");
      } else {
        asm volatile("s_waitcnt vmcnt(0)" ::: "memory");
      }
      __builtin_amdgcn_s_barrier();

      short8 af[2][2];
      if (p == 0) {
#pragma unroll
        for (int j = 0; j < 4; ++j)
#pragma unroll
          for (int ks = 0; ks < 2; ++ks) {
            const int ko = (ks * 32 + ((lane >> 4) << 3)) ^ ((lane & 7) << 3);
            bfr[j * 2 + ks] = *(const short8*)
                &Bs[cur][(wn * 64 + j * 16 + (lane & 15)) * 64 + ko];
          }
      }
#pragma unroll
      for (int ii = 0; ii < 2; ++ii)
#pragma unroll
        for (int ks = 0; ks < 2; ++ks) {
          const int ko = (ks * 32 + ((lane >> 4) << 3)) ^ ((lane & 7) << 3);
          af[ii][ks] = *(const short8*)
              &As[cur][(wm * 128 + (2 * p + ii) * 16 + (lane & 15)) * 64 + ko];
        }

      asm volatile("s_waitcnt lgkmcnt(0)" ::: "memory");
      __builtin_amdgcn_s_setprio(1);
#pragma unroll
      for (int ii = 0; ii < 2; ++ii)
#pragma unroll
        for (int ks = 0; ks < 2; ++ks)
#pragma unroll
          for (int j = 0; j < 4; ++j)
            acc[2 * p + ii][j] = __builtin_amdgcn_mfma_f32_16x16x32_bf16(
                af[ii][ks], bfr[j * 2 + ks], acc[2 * p + ii][j], 0, 0, 0);
      __builtin_amdgcn_s_setprio(0);
      __builtin_amdgcn_s_barrier();
    }
  }

  if (!fuseW3) {
#pragma unroll
    for (int j = 0; j < 4; ++j) {
      const int c = bcol0 + wn * 64 + j * 16 + (lane & 15);
      const float bia = bias[c];
      float wa = 0.f, wb = 0.f;
      if (rank2) {
        wa = wr0[c];
        wb = wr1[c];
      }
#pragma unroll
      for (int i = 0; i < 8; ++i) {
        const long rb = arow0 + wm * 128 + i * 16 + ((lane >> 4) << 2);
#pragma unroll
        for (int g = 0; g < 4; ++g) {
          const long r = rb + g;
          float v = acc[i][j][g] + bia;
          if (rank2) v += srow[r] * wa + ptv[r] * wb;
          v = v > 0.f ? v : 0.01f * v;
          C[r * N + c] = __float2bfloat16(v);
        }
      }
    }
  } else {
    float bia[4], w3v[4];
#pragma unroll
    for (int j = 0; j < 4; ++j) {
      const int c = bcol0 + wn * 64 + j * 16 + (lane & 15);
      bia[j] = bias[c];
      w3v[j] = W3[c];
    }
#pragma unroll
    for (int i = 0; i < 8; ++i) {
#pragma unroll
      for (int g = 0; g < 4; ++g) {
        float ps = 0.f;
#pragma unroll
        for (int j = 0; j < 4; ++j) {
          float v = acc[i][j][g] + bia[j];
          v = v > 0.f ? v : 0.01f * v;
          ps += v * w3v[j];
        }
        ps += __shfl_xor(ps, 1);
        ps += __shfl_xor(ps, 2);
        ps += __shfl_xor(ps, 4);
        ps += __shfl_xor(ps, 8);
        if ((lane & 15) == 0) {
          const long r = arow0 + wm * 128 + i * 16 + ((lane >> 4) << 2) + g;
          atomicAdd(&scoreOut[r], ps);
        }
      }
    }
  }
#undef STAGE_A
#undef STAGE_B
}

// ---------------------------------------------------------------------------
// softmax + argmax reductions (b3 is a constant shift -> cancels in softmax
// and does not change argmax; omitted).
// ---------------------------------------------------------------------------
__global__ __launch_bounds__(256) void redmax_kernel(
    const float* __restrict__ score, float* __restrict__ pmax,
    int* __restrict__ pidx) {
  const int t = threadIdx.x, b = blockIdx.x;
  float m = -1e30f;
  int mi = 0;
#pragma unroll
  for (int u = 0; u < 2; ++u) {
    int i = b * 512 + u * 256 + t;
    float v = score[i];
    if (v > m) {
      m = v;
      mi = i;
    }
  }
  __shared__ float sm[4];
  __shared__ int si[4];
#pragma unroll
  for (int off = 32; off; off >>= 1) {
    float om = __shfl_down(m, off);
    int oi = __shfl_down(mi, off);
    if (om > m || (om == m && oi < mi)) {
      m = om;
      mi = oi;
    }
  }
  const int lane = t & 63, w = t >> 6;
  if (lane == 0) {
    sm[w] = m;
    si[w] = mi;
  }
  __syncthreads();
  if (t == 0) {
    for (int w2 = 1; w2 < 4; ++w2)
      if (sm[w2] > m || (sm[w2] == m && si[w2] < mi)) {
        m = sm[w2];
        mi = si[w2];
      }
    pmax[b] = m;
    pidx[b] = mi;
  }
}

__global__ __launch_bounds__(64) void finmax_kernel(
    const float* __restrict__ pmax, const int* __restrict__ pidx,
    float* __restrict__ gscal, float* __restrict__ out_idx) {
  const int t = threadIdx.x;
  float m = pmax[t];
  int mi = pidx[t];
#pragma unroll
  for (int off = 32; off; off >>= 1) {
    float om = __shfl_down(m, off);
    int oi = __shfl_down(mi, off);
    if (om > m || (om == m && oi < mi)) {
      m = om;
      mi = oi;
    }
  }
  if (t == 0) {
    gscal[0] = m;
    out_idx[0] = (float)mi;
  }
}

__global__ __launch_bounds__(256) void expsum_kernel(
    const float* __restrict__ score, const float* __restrict__ gscal,
    float* __restrict__ e, float* __restrict__ psum) {
  const int t = threadIdx.x, b = blockIdx.x;
  const float gmax = gscal[0];
  float s = 0.f;
#pragma unroll
  for (int u = 0; u < 2; ++u) {
    int i = b * 512 + u * 256 + t;
    float v = expf(score[i] - gmax);
    e[i] = v;
    s += v;
  }
#pragma unroll
  for (int off = 32; off; off >>= 1) s += __shfl_down(s, off);
  __shared__ float sm[4];
  const int lane = t & 63, w = t >> 6;
  if (lane == 0) sm[w] = s;
  __syncthreads();
  if (t == 0) psum[b] = sm[0] + sm[1] + sm[2] + sm[3];
}

__global__ __launch_bounds__(64) void finsum_kernel(const float* __restrict__ psum,
                                                    float* __restrict__ gscal) {
  float s = psum[threadIdx.x];
#pragma unroll
  for (int off = 32; off; off >>= 1) s += __shfl_down(s, off);
  if (threadIdx.x == 0) gscal[1] = 1.0f / s;
}

__global__ __launch_bounds__(256) void scale_kernel(float* __restrict__ e,
                                                    const float* __restrict__ gscal) {
  const float inv = gscal[1];
  const int i = blockIdx.x * 512 + threadIdx.x;
  e[i] *= inv;
  e[i + 256] *= inv;
}

// ---------------------------------------------------------------------------
extern "C" void kernel_launch(void* const* d_in, const int* in_sizes, int n_in,
                              void* d_out, int out_size, void* d_ws,
                              size_t ws_size, hipStream_t stream) {
  const float* x_m = (const float*)d_in[0];
  const float* x_op = (const float*)d_in[1];
  const float* job_srpt = (const float*)d_in[2];
  const float* pt = (const float*)d_in[3];
  const float* W0 = (const float*)d_in[4];
  const float* b0 = (const float*)d_in[5];
  const float* W1 = (const float*)d_in[6];
  const float* b1 = (const float*)d_in[7];
  const float* W2 = (const float*)d_in[8];
  const float* b2 = (const float*)d_in[9];
  const float* W3 = (const float*)d_in[10];
  const int* m_ids = (const int*)d_in[12];
  const int* op_idx = (const int*)d_in[13];
  const int* job_ids = (const int*)d_in[14];

  const int M = 32768;

  char* p = (char*)d_ws;
  __hip_bfloat16* feat = (__hip_bfloat16*)p;            p += (size_t)M * 2048 * 2;
  __hip_bfloat16* hA = (__hip_bfloat16*)p;              p += (size_t)M * 1024 * 2;
  __hip_bfloat16* hB = (__hip_bfloat16*)p;              p += (size_t)M * 1024 * 2;
  __hip_bfloat16* Wt0 = (__hip_bfloat16*)p;             p += (size_t)1024 * 2048 * 2;
  __hip_bfloat16* Wt1 = (__hip_bfloat16*)p;             p += (size_t)1024 * 1024 * 2;
  __hip_bfloat16* Wt2 = (__hip_bfloat16*)p;             p += (size_t)1024 * 1024 * 2;
  float* srow = (float*)p;                              p += (size_t)M * 4;
  float* score = (float*)p;                             p += (size_t)M * 4;
  float* pmax = (float*)p;                              p += 256;
  int* pidx = (int*)p;                                  p += 256;
  float* psum = (float*)p;                              p += 256;
  float* gscal = (float*)p;                             p += 256;

  float* probs = (float*)d_out;
  float* out_idx = probs + M;

  feat_kernel<<<M, 256, 0, stream>>>(x_m, x_op, job_srpt, m_ids, op_idx,
                                     job_ids, feat, srow);
  wconv_kernel<<<dim3(32, 16), 256, 0, stream>>>(W0, Wt0, 2048);
  wconv_kernel<<<dim3(16, 16), 256, 0, stream>>>(W1, Wt1, 1024);
  wconv_kernel<<<dim3(16, 16), 256, 0, stream>>>(W2, Wt2, 1024);
  hipMemsetAsync(score, 0, (size_t)M * 4, stream);

  gemm_kernel<<<dim3(128, 4), 512, 0, stream>>>(
      feat, Wt0, hA, b0, M, 1024, 2048, 1, W0 + (size_t)2048 * 1024,
      W0 + (size_t)2049 * 1024, srow, pt, 0, nullptr, nullptr);
  gemm_kernel<<<dim3(128, 4), 512, 0, stream>>>(hA, Wt1, hB, b1, M, 1024, 1024,
                                                0, nullptr, nullptr, nullptr,
                                                nullptr, 0, nullptr, nullptr);
  gemm_kernel<<<dim3(128, 4), 512, 0, stream>>>(hB, Wt2, nullptr, b2, M, 1024,
                                                1024, 0, nullptr, nullptr,
                                                nullptr, nullptr, 1, W3, score);

  redmax_kernel<<<64, 256, 0, stream>>>(score, pmax, pidx);
  finmax_kernel<<<1, 64, 0, stream>>>(pmax, pidx, gscal, out_idx);
  expsum_kernel<<<64, 256, 0, stream>>>(score, gscal, probs, psum);
  finsum_kernel<<<1, 64, 0, stream>>>(psum, gscal);
  scale_kernel<<<64, 256, 0, stream>>>(probs, gscal);
}

// Round 5
// 409.899 us; speedup vs baseline: 1.4189x; 1.0733x over previous
//
#include <hip/hip_runtime.h>
#include <hip/hip_bf16.h>

typedef __attribute__((ext_vector_type(8))) short short8;
typedef __attribute__((ext_vector_type(4))) float f32x4;

#define GL2LDS16(g, l)                                                         \
  __builtin_amdgcn_global_load_lds(                                            \
      (const __attribute__((address_space(1))) unsigned int*)(g),              \
      (__attribute__((address_space(3))) unsigned int*)(l), 16, 0, 0)

// Inline-asm ds_read_b128: invisible to the compiler's waitcnt pass (no
// memory clobber), so our counted s_waitcnt vmcnt(N) is not followed by a
// compiler-inserted vmcnt(0) drain for the outstanding LDS-DMA
// (global_load_lds) ops. lgkmcnt is handled manually (rule #18).
__device__ __forceinline__ short8 lds_read_b128(const __hip_bfloat16* p) {
  short8 v;
  asm volatile("ds_read_b128 %0, %1"
               : "=v"(v)
               : "v"((unsigned)(uintptr_t)p));
  return v;
}

// ---------------------------------------------------------------------------
// feat[row][0:1024] = x_m[m_ids[row]]; feat[row][1024:2048] = x_op[op_idx[row]]
// (bf16). Also srow[row] = job_srpt[job_ids[row]] (fp32).
// ---------------------------------------------------------------------------
__global__ __launch_bounds__(256) void feat_kernel(
    const float* __restrict__ x_m, const float* __restrict__ x_op,
    const float* __restrict__ job_srpt, const int* __restrict__ m_ids,
    const int* __restrict__ op_idx, const int* __restrict__ job_ids,
    __hip_bfloat16* __restrict__ feat, float* __restrict__ srow) {
  const int row = blockIdx.x;
  const int t = threadIdx.x;
  const int j0 = t * 8;
  const float* src;
  if (j0 < 1024)
    src = x_m + (long)m_ids[row] * 1024 + j0;
  else
    src = x_op + (long)op_idx[row] * 1024 + (j0 - 1024);
  float4 v0 = *(const float4*)src;
  float4 v1 = *(const float4*)(src + 4);
  union {
    __hip_bfloat16 h[8];
    int4 i4;
  } u;
  u.h[0] = __float2bfloat16(v0.x);
  u.h[1] = __float2bfloat16(v0.y);
  u.h[2] = __float2bfloat16(v0.z);
  u.h[3] = __float2bfloat16(v0.w);
  u.h[4] = __float2bfloat16(v1.x);
  u.h[5] = __float2bfloat16(v1.y);
  u.h[6] = __float2bfloat16(v1.z);
  u.h[7] = __float2bfloat16(v1.w);
  *(int4*)&feat[(long)row * 2048 + j0] = u.i4;
  if (t == 0) srow[row] = job_srpt[job_ids[row]];
}

// ---------------------------------------------------------------------------
// Transpose-convert fp32 W[K][1024] -> bf16 Wt[1024][K].
// ---------------------------------------------------------------------------
__global__ __launch_bounds__(256) void wconv_kernel(
    const float* __restrict__ W, __hip_bfloat16* __restrict__ Wt, int K) {
  __shared__ float tile[64][65];
  const int kb = blockIdx.x * 64;
  const int nb = blockIdx.y * 64;
  const int t = threadIdx.x;
#pragma unroll
  for (int it = 0; it < 16; ++it) {
    int idx = it * 256 + t;
    int kk = idx >> 6, nn = idx & 63;
    tile[kk][nn] = W[(long)(kb + kk) * 1024 + nb + nn];
  }
  __syncthreads();
#pragma unroll
  for (int it = 0; it < 16; ++it) {
    int idx = it * 256 + t;
    int nn = idx >> 6, kk = idx & 63;
    Wt[(long)(nb + nn) * K + kb + kk] = __float2bfloat16(tile[kk][nn]);
  }
}

// ---------------------------------------------------------------------------
// C[M][N] = lrelu(A[M][K] @ Bt[N][K]^T + bias (+ rank2 srpt/pt correction))
// 256x256 tile, BK=64, 8 waves (2Mx4N), double-buffered LDS.
// 8-phase schedule (4 phases per K-tile), counted vmcnt(4), raw s_barrier,
// inline-asm ds_read_b128 + manual lgkmcnt(0) + sched_barrier(0) (rule #18).
// Chunk schedule (tile kt+1 staged during tile kt):
//   ph0: B-q0,B-q1  ph1: B-q2,B-q3  ph2: A-c0,A-c1  ph3: A-c2,A-c3
// A-chunk p = rows [32p,32p+32) U [128+32p,128+32p+32); B-quarter q = 64 cols.
// vmcnt(4) = 2 phases slack; chunk-by-chunk hazard check done for steady
// state, prologue, and last tile (vmcnt(0)). LDS 16B-chunk XOR swizzle,
// both-sides (pre-swizzled global source + XOR on read), rule #21.
// ---------------------------------------------------------------------------
__global__ __launch_bounds__(512, 2) void gemm_kernel(
    const __hip_bfloat16* __restrict__ A, const __hip_bfloat16* __restrict__ Bt,
    __hip_bfloat16* __restrict__ C, const float* __restrict__ bias, int M,
    int N, int K, int rank2, const float* __restrict__ wr0,
    const float* __restrict__ wr1, const float* __restrict__ srow,
    const float* __restrict__ ptv, int fuseW3,
    const float* __restrict__ W3, float* __restrict__ scoreOut) {
  __shared__ __align__(16) __hip_bfloat16 As[2][256 * 64];
  __shared__ __align__(16) __hip_bfloat16 Bs[2][256 * 64];
  const int t = threadIdx.x;
  const int lane = t & 63;
  const int wid = t >> 6;   // 0..7
  const int wm = wid >> 2;  // 0..1  (M half: 128 rows)
  const int wn = wid & 3;   // 0..3  (N quarter: 64 cols)
  const long arow0 = (long)blockIdx.x * 256;
  const int bcol0 = blockIdx.y * 256;
  const int NT = K >> 6;

  // staging geometry (1 load/thread per 8KB chunk, LDS dest linear in t)
  const int sa_row = ((t >> 8) * 128) + ((t >> 3) & 31);  // + p*32
  const int sb_row = t >> 3;                              // + q*64
  const int scol = ((t & 7) ^ ((t >> 3) & 7)) * 8;        // pre-swizzled col

#define STAGE_A(buf, kt1, p)                                                   \
  GL2LDS16(A + (arow0 + sa_row + (p) * 32) * (long)K + (kt1) * 64 + scol,      \
           &As[buf][(t >> 8) * 8192 + (p) * 2048 + (t & 255) * 8])
#define STAGE_B(buf, kt1, q)                                                   \
  GL2LDS16(Bt + (long)(bcol0 + sb_row + (q) * 64) * (long)K + (kt1) * 64 + scol, \
           &Bs[buf][(q) * 4096 + t * 8])

  f32x4 acc[8][4] = {};
  short8 bfr[8];

  // prologue: stage all of tile 0 (order matches steady state: B0..B3,A0..A3)
#pragma unroll
  for (int q = 0; q < 4; ++q) STAGE_B(0, 0, q);
#pragma unroll
  for (int p = 0; p < 4; ++p) STAGE_A(0, 0, p);

  for (int kt = 0; kt < NT; ++kt) {
    const int cur = kt & 1;
    const bool pre = (kt + 1) < NT;
#pragma unroll
    for (int p = 0; p < 4; ++p) {
      if (pre) {
        if (p == 0) { STAGE_B(cur ^ 1, kt + 1, 0); STAGE_B(cur ^ 1, kt + 1, 1); }
        if (p == 1) { STAGE_B(cur ^ 1, kt + 1, 2); STAGE_B(cur ^ 1, kt + 1, 3); }
        if (p == 2) { STAGE_A(cur ^ 1, kt + 1, 0); STAGE_A(cur ^ 1, kt + 1, 1); }
        if (p == 3) { STAGE_A(cur ^ 1, kt + 1, 2); STAGE_A(cur ^ 1, kt + 1, 3); }
        asm volatile("s_waitcnt vmcnt(4)" ::: "memory");
      } else {
        asm volatile("s_waitcnt vmcnt(0)" ::: "memory");
      }
      __builtin_amdgcn_s_barrier();

      short8 af[2][2];
      if (p == 0) {
#pragma unroll
        for (int j = 0; j < 4; ++j)
#pragma unroll
          for (int ks = 0; ks < 2; ++ks) {
            const int ko = (ks * 32 + ((lane >> 4) << 3)) ^ ((lane & 7) << 3);
            bfr[j * 2 + ks] =
                lds_read_b128(&Bs[cur][(wn * 64 + j * 16 + (lane & 15)) * 64 + ko]);
          }
      }
#pragma unroll
      for (int ii = 0; ii < 2; ++ii)
#pragma unroll
        for (int ks = 0; ks < 2; ++ks) {
          const int ko = (ks * 32 + ((lane >> 4) << 3)) ^ ((lane & 7) << 3);
          af[ii][ks] = lds_read_b128(
              &As[cur][(wm * 128 + (2 * p + ii) * 16 + (lane & 15)) * 64 + ko]);
        }

      asm volatile("s_waitcnt lgkmcnt(0)" ::: "memory");
      __builtin_amdgcn_sched_barrier(0);  // rule #18: pin MFMAs below the wait
      __builtin_amdgcn_s_setprio(1);
#pragma unroll
      for (int ii = 0; ii < 2; ++ii)
#pragma unroll
        for (int ks = 0; ks < 2; ++ks)
#pragma unroll
          for (int j = 0; j < 4; ++j)
            acc[2 * p + ii][j] = __builtin_amdgcn_mfma_f32_16x16x32_bf16(
                af[ii][ks], bfr[j * 2 + ks], acc[2 * p + ii][j], 0, 0, 0);
      __builtin_amdgcn_s_setprio(0);
      __builtin_amdgcn_s_barrier();
    }
  }

  if (!fuseW3) {
#pragma unroll
    for (int j = 0; j < 4; ++j) {
      const int c = bcol0 + wn * 64 + j * 16 + (lane & 15);
      const float bia = bias[c];
      float wa = 0.f, wb = 0.f;
      if (rank2) {
        wa = wr0[c];
        wb = wr1[c];
      }
#pragma unroll
      for (int i = 0; i < 8; ++i) {
        const long rb = arow0 + wm * 128 + i * 16 + ((lane >> 4) << 2);
#pragma unroll
        for (int g = 0; g < 4; ++g) {
          const long r = rb + g;
          float v = acc[i][j][g] + bia;
          if (rank2) v += srow[r] * wa + ptv[r] * wb;
          v = v > 0.f ? v : 0.01f * v;
          C[r * N + c] = __float2bfloat16(v);
        }
      }
    }
  } else {
    float bia[4], w3v[4];
#pragma unroll
    for (int j = 0; j < 4; ++j) {
      const int c = bcol0 + wn * 64 + j * 16 + (lane & 15);
      bia[j] = bias[c];
      w3v[j] = W3[c];
    }
#pragma unroll
    for (int i = 0; i < 8; ++i) {
#pragma unroll
      for (int g = 0; g < 4; ++g) {
        float ps = 0.f;
#pragma unroll
        for (int j = 0; j < 4; ++j) {
          float v = acc[i][j][g] + bia[j];
          v = v > 0.f ? v : 0.01f * v;
          ps += v * w3v[j];
        }
        ps += __shfl_xor(ps, 1);
        ps += __shfl_xor(ps, 2);
        ps += __shfl_xor(ps, 4);
        ps += __shfl_xor(ps, 8);
        if ((lane & 15) == 0) {
          const long r = arow0 + wm * 128 + i * 16 + ((lane >> 4) << 2) + g;
          atomicAdd(&scoreOut[r], ps);
        }
      }
    }
  }
#undef STAGE_A
#undef STAGE_B
}

// ---------------------------------------------------------------------------
// softmax + argmax reductions (b3 is a constant shift -> cancels in softmax
// and does not change argmax; omitted).
// ---------------------------------------------------------------------------
__global__ __launch_bounds__(256) void redmax_kernel(
    const float* __restrict__ score, float* __restrict__ pmax,
    int* __restrict__ pidx) {
  const int t = threadIdx.x, b = blockIdx.x;
  float m = -1e30f;
  int mi = 0;
#pragma unroll
  for (int u = 0; u < 2; ++u) {
    int i = b * 512 + u * 256 + t;
    float v = score[i];
    if (v > m) {
      m = v;
      mi = i;
    }
  }
  __shared__ float sm[4];
  __shared__ int si[4];
#pragma unroll
  for (int off = 32; off; off >>= 1) {
    float om = __shfl_down(m, off);
    int oi = __shfl_down(mi, off);
    if (om > m || (om == m && oi < mi)) {
      m = om;
      mi = oi;
    }
  }
  const int lane = t & 63, w = t >> 6;
  if (lane == 0) {
    sm[w] = m;
    si[w] = mi;
  }
  __syncthreads();
  if (t == 0) {
    for (int w2 = 1; w2 < 4; ++w2)
      if (sm[w2] > m || (sm[w2] == m && si[w2] < mi)) {
        m = sm[w2];
        mi = si[w2];
      }
    pmax[b] = m;
    pidx[b] = mi;
  }
}

__global__ __launch_bounds__(64) void finmax_kernel(
    const float* __restrict__ pmax, const int* __restrict__ pidx,
    float* __restrict__ gscal, float* __restrict__ out_idx) {
  const int t = threadIdx.x;
  float m = pmax[t];
  int mi = pidx[t];
#pragma unroll
  for (int off = 32; off; off >>= 1) {
    float om = __shfl_down(m, off);
    int oi = __shfl_down(mi, off);
    if (om > m || (om == m && oi < mi)) {
      m = om;
      mi = oi;
    }
  }
  if (t == 0) {
    gscal[0] = m;
    out_idx[0] = (float)mi;
  }
}

__global__ __launch_bounds__(256) void expsum_kernel(
    const float* __restrict__ score, const float* __restrict__ gscal,
    float* __restrict__ e, float* __restrict__ psum) {
  const int t = threadIdx.x, b = blockIdx.x;
  const float gmax = gscal[0];
  float s = 0.f;
#pragma unroll
  for (int u = 0; u < 2; ++u) {
    int i = b * 512 + u * 256 + t;
    float v = expf(score[i] - gmax);
    e[i] = v;
    s += v;
  }
#pragma unroll
  for (int off = 32; off; off >>= 1) s += __shfl_down(s, off);
  __shared__ float sm[4];
  const int lane = t & 63, w = t >> 6;
  if (lane == 0) sm[w] = s;
  __syncthreads();
  if (t == 0) psum[b] = sm[0] + sm[1] + sm[2] + sm[3];
}

__global__ __launch_bounds__(64) void finsum_kernel(const float* __restrict__ psum,
                                                    float* __restrict__ gscal) {
  float s = psum[threadIdx.x];
#pragma unroll
  for (int off = 32; off; off >>= 1) s += __shfl_down(s, off);
  if (threadIdx.x == 0) gscal[1] = 1.0f / s;
}

__global__ __launch_bounds__(256) void scale_kernel(float* __restrict__ e,
                                                    const float* __restrict__ gscal) {
  const float inv = gscal[1];
  const int i = blockIdx.x * 512 + threadIdx.x;
  e[i] *= inv;
  e[i + 256] *= inv;
}

// ---------------------------------------------------------------------------
extern "C" void kernel_launch(void* const* d_in, const int* in_sizes, int n_in,
                              void* d_out, int out_size, void* d_ws,
                              size_t ws_size, hipStream_t stream) {
  const float* x_m = (const float*)d_in[0];
  const float* x_op = (const float*)d_in[1];
  const float* job_srpt = (const float*)d_in[2];
  const float* pt = (const float*)d_in[3];
  const float* W0 = (const float*)d_in[4];
  const float* b0 = (const float*)d_in[5];
  const float* W1 = (const float*)d_in[6];
  const float* b1 = (const float*)d_in[7];
  const float* W2 = (const float*)d_in[8];
  const float* b2 = (const float*)d_in[9];
  const float* W3 = (const float*)d_in[10];
  const int* m_ids = (const int*)d_in[12];
  const int* op_idx = (const int*)d_in[13];
  const int* job_ids = (const int*)d_in[14];

  const int M = 32768;

  char* p = (char*)d_ws;
  __hip_bfloat16* feat = (__hip_bfloat16*)p;            p += (size_t)M * 2048 * 2;
  __hip_bfloat16* hA = (__hip_bfloat16*)p;              p += (size_t)M * 1024 * 2;
  __hip_bfloat16* hB = (__hip_bfloat16*)p;              p += (size_t)M * 1024 * 2;
  __hip_bfloat16* Wt0 = (__hip_bfloat16*)p;             p += (size_t)1024 * 2048 * 2;
  __hip_bfloat16* Wt1 = (__hip_bfloat16*)p;             p += (size_t)1024 * 1024 * 2;
  __hip_bfloat16* Wt2 = (__hip_bfloat16*)p;             p += (size_t)1024 * 1024 * 2;
  float* srow = (float*)p;                              p += (size_t)M * 4;
  float* score = (float*)p;                             p += (size_t)M * 4;
  float* pmax = (float*)p;                              p += 256;
  int* pidx = (int*)p;                                  p += 256;
  float* psum = (float*)p;                              p += 256;
  float* gscal = (float*)p;                             p += 256;

  float* probs = (float*)d_out;
  float* out_idx = probs + M;

  feat_kernel<<<M, 256, 0, stream>>>(x_m, x_op, job_srpt, m_ids, op_idx,
                                     job_ids, feat, srow);
  wconv_kernel<<<dim3(32, 16), 256, 0, stream>>>(W0, Wt0, 2048);
  wconv_kernel<<<dim3(16, 16), 256, 0, stream>>>(W1, Wt1, 1024);
  wconv_kernel<<<dim3(16, 16), 256, 0, stream>>>(W2, Wt2, 1024);
  hipMemsetAsync(score, 0, (size_t)M * 4, stream);

  gemm_kernel<<<dim3(128, 4), 512, 0, stream>>>(
      feat, Wt0, hA, b0, M, 1024, 2048, 1, W0 + (size_t)2048 * 1024,
      W0 + (size_t)2049 * 1024, srow, pt, 0, nullptr, nullptr);
  gemm_kernel<<<dim3(128, 4), 512, 0, stream>>>(hA, Wt1, hB, b1, M, 1024, 1024,
                                                0, nullptr, nullptr, nullptr,
                                                nullptr, 0, nullptr, nullptr);
  gemm_kernel<<<dim3(128, 4), 512, 0, stream>>>(hB, Wt2, nullptr, b2, M, 1024,
                                                1024, 0, nullptr, nullptr,
                                                nullptr, nullptr, 1, W3, score);

  redmax_kernel<<<64, 256, 0, stream>>>(score, pmax, pidx);
  finmax_kernel<<<1, 64, 0, stream>>>(pmax, pidx, gscal, out_idx);
  expsum_kernel<<<64, 256, 0, stream>>>(score, gscal, probs, psum);
  finsum_kernel<<<1, 64, 0, stream>>>(psum, gscal);
  scale_kernel<<<64, 256, 0, stream>>>(probs, gscal);
}